// Round 16
// baseline (902.549 us; speedup 1.0000x reference)
//
#include <hip/hip_runtime.h>

typedef _Float16 f16x8 __attribute__((ext_vector_type(8)));
typedef float f32x4 __attribute__((ext_vector_type(4)));

#define NS 131072
#define KC 2048
#define DD 256
#define SMARGIN 0.12f
#define ACHUNK 128

// ---------------- helpers ----------------
__device__ __forceinline__ void async16(void* lds, const void* g) {
  __builtin_amdgcn_global_load_lds(
      (const __attribute__((address_space(1))) unsigned*)g,
      (__attribute__((address_space(3))) unsigned*)lds, 16, 0, 0);
}

__device__ __forceinline__ void rec_ins(float& m1, float& m2, float& m3,
                                        int& i1, int& i2, float q, int i) {
  if (q < m1 || (q == m1 && i < i1)) {
    m3 = m2; m2 = m1; i2 = i1; m1 = q; i1 = i;
  } else if (q < m2 || (q == m2 && i < i2)) {
    m3 = m2; m2 = q; i2 = i;
  } else if (q < m3) {
    m3 = q;
  }
}

// exact fp32 distance: bit-identical to the verified round-2/3 chain
__device__ __forceinline__ float dist_exact(const float* __restrict__ E,
                                            const float* __restrict__ C,
                                            const float* __restrict__ x2,
                                            const float* __restrict__ c2,
                                            int row, int j) {
  const float* e = E + (size_t)row * DD;
  const float* c = C + (size_t)j * DD;
  float acc = 0.0f;
  #pragma unroll 8
  for (int k = 0; k < DD; ++k) acc = fmaf(e[k], c[k], acc);
  return __fadd_rn(__fsub_rn(x2[row], __fmul_rn(2.0f, acc)), c2[j]);
}

// ---------------- fused prep: coalesced load + fp16 + numpy-exact norm --
__global__ __launch_bounds__(256) void k_prep(const float* __restrict__ A,
                                              float* __restrict__ out,
                                              unsigned short* __restrict__ AX) {
  __shared__ float sf[32][260];
  const int tid = threadIdx.x;
  const size_t base = (size_t)blockIdx.x * 32 * 256;
  const float4* ga = (const float4*)(A + base);
  ushort4* gx = (ushort4*)(AX + base);
  #pragma unroll
  for (int i = 0; i < 8; ++i) {
    int idx = tid + i * 256;
    float4 v = ga[idx];
    int row = idx >> 6, c4 = idx & 63;
    *(float4*)&sf[row][c4 * 4] = v;
    union { _Float16 h; unsigned short u; } c0, c1, c2, c3;
    c0.h = (_Float16)v.x; c1.h = (_Float16)v.y;
    c2.h = (_Float16)v.z; c3.h = (_Float16)v.w;
    gx[idx] = make_ushort4(c0.u, c1.u, c2.u, c3.u);
  }
  __syncthreads();
  const int r = tid >> 3, l = tid & 7;
  float halfs[2];
  #pragma unroll
  for (int h = 0; h < 2; ++h) {
    float x = sf[r][h * 128 + l];
    float racc = __fmul_rn(x, x);
    #pragma unroll
    for (int i = 8; i < 128; i += 8) {
      float y = sf[r][h * 128 + i + l];
      racc = __fadd_rn(racc, __fmul_rn(y, y));
    }
    float t = __fadd_rn(racc, __shfl_xor(racc, 1));
    t = __fadd_rn(t, __shfl_xor(t, 2));
    t = __fadd_rn(t, __shfl_xor(t, 4));
    halfs[h] = t;
  }
  if (l == 0) out[blockIdx.x * 32 + r] = __fadd_rn(halfs[0], halfs[1]);
}

// ---------------- fused MFMA screen: 128 rows x ALL 2048 centers --------
// A (4 slabs, 64KB) resident in LDS; B streams 16KB slabs, 2-deep counted
// vmcnt pipeline; per-thread deferred top-3; classification fused in.
// c2 read DIRECT from global (L2-resident) — no LDS staging (r15 bug).
__global__ __launch_bounds__(256) void k_screenF(
    const unsigned short* __restrict__ EX, const unsigned short* __restrict__ CX,
    const float* __restrict__ c2, int* __restrict__ labels,
    int4* __restrict__ pairs, int* __restrict__ scans,
    int* __restrict__ npairs, int* __restrict__ nscan, int* __restrict__ cnt,
    int rowOff) {
  __shared__ char smem[98304];  // A 64K | B 2x16K
  char* Alds = smem;
  char* Blds = smem + 65536;

  const int tid = threadIdx.x;
  const int wave = tid >> 6, lane = tid & 63;
  const int ln15 = lane & 15, ln4 = lane >> 4;
  const int rowA0 = blockIdx.x * 128;
  const int rsw = ((lane & 7) ^ (lane >> 3)) << 3;   // src pre-swizzle (elems)
  const int rowterm = (wave * 32 + (lane >> 3)) * 256 + rsw;

#define VMW4() do { asm volatile("s_waitcnt vmcnt(4)" ::: "memory"); \
                    __builtin_amdgcn_sched_barrier(0); } while (0)
#define VMW0() do { asm volatile("s_waitcnt vmcnt(0)" ::: "memory"); \
                    __builtin_amdgcn_sched_barrier(0); } while (0)
#define BAR() __builtin_amdgcn_s_barrier();

#define STAGE_B(cb_, s_) {                                                 \
    char* _d = Blds + ((s_) & 1) * 16384 + wave * 4096;                    \
    const unsigned short* _s = CX + (size_t)(cb_) * 32768 + rowterm + (s_) * 64; \
    async16(_d, _s); async16(_d + 1024, _s + 2048);                        \
    async16(_d + 2048, _s + 4096); async16(_d + 3072, _s + 6144); }

  // prologue: A (64KB), B slabs (cb0,s0) and (cb0,s1)
  #pragma unroll
  for (int s = 0; s < 4; ++s) {
    char* d = Alds + s * 16384 + wave * 4096;
    const unsigned short* sp = EX + (size_t)rowA0 * 256 + rowterm + s * 64;
    async16(d, sp); async16(d + 1024, sp + 2048);
    async16(d + 2048, sp + 4096); async16(d + 3072, sp + 6144);
  }
  STAGE_B(0, 0); STAGE_B(0, 1);

  // per-thread running top-3 state (rows m*16 + ln4*4 + rr within wave)
  float M1[2][4], M2[2][4], M3[2][4];
  int I1[2][4], I2[2][4];
  #pragma unroll
  for (int m = 0; m < 2; ++m)
    #pragma unroll
    for (int rr = 0; rr < 4; ++rr) {
      M1[m][rr] = 3.4e38f; M2[m][rr] = 3.4e38f; M3[m][rr] = 3.4e38f;
      I1[m][rr] = 0x7fffffff; I2[m][rr] = 0x7fffffff;
    }

  const int arow = (wave * 32 + ln15) * 128;
  const int brow = ln15 * 128;
  const int slot0 = ((0 * 4 + ln4) ^ (ln15 & 7)) << 4;
  const int slot1 = ((1 * 4 + ln4) ^ (ln15 & 7)) << 4;

#define COMPUTE(s_) {                                                      \
    const int _bb = ((s_) & 1) * 16384;                                    \
    _Pragma("unroll")                                                      \
    for (int ks = 0; ks < 2; ++ks) {                                       \
      const int _sl = ks ? slot1 : slot0;                                  \
      f16x8 a[2], bb[8];                                                   \
      _Pragma("unroll")                                                    \
      for (int m = 0; m < 2; ++m)                                          \
        a[m] = *(const f16x8*)(Alds + (s_) * 16384 + arow + m * 2048 + _sl); \
      _Pragma("unroll")                                                    \
      for (int n = 0; n < 8; ++n)                                          \
        bb[n] = *(const f16x8*)(Blds + _bb + brow + n * 2048 + _sl);       \
      _Pragma("unroll")                                                    \
      for (int m = 0; m < 2; ++m)                                          \
        _Pragma("unroll")                                                  \
        for (int n = 0; n < 8; ++n)                                        \
          acc[m][n] = __builtin_amdgcn_mfma_f32_16x16x32_f16(              \
              a[m], bb[n], acc[m][n], 0, 0, 0);                            \
    } }

  for (int cb = 0; cb < 16; ++cb) {
    f32x4 acc[2][8];
    #pragma unroll
    for (int m = 0; m < 2; ++m)
      #pragma unroll
      for (int n = 0; n < 8; ++n) acc[m][n] = (f32x4){0.f, 0.f, 0.f, 0.f};

    VMW4(); BAR(); COMPUTE(0); BAR(); STAGE_B(cb, 2);
    VMW4(); BAR(); COMPUTE(1); BAR(); STAGE_B(cb, 3);
    VMW4(); BAR(); COMPUTE(2); BAR(); if (cb < 15) STAGE_B(cb + 1, 0);
    if (cb != 15) { VMW4(); } else { VMW0(); }
    BAR(); COMPUTE(3); BAR(); if (cb < 15) STAGE_B(cb + 1, 1);

    // epilogue for this col-block: candidates in ascending col order
    float c2v[8];
    #pragma unroll
    for (int n = 0; n < 8; ++n)
      c2v[n] = c2[cb * 128 + n * 16 + ln15];
    #pragma unroll
    for (int m = 0; m < 2; ++m)
      #pragma unroll
      for (int rr = 0; rr < 4; ++rr)
        #pragma unroll
        for (int n = 0; n < 8; ++n) {
          float q = fmaf(-2.0f, acc[m][n][rr], c2v[n]);
          rec_ins(M1[m][rr], M2[m][rr], M3[m][rr], I1[m][rr], I2[m][rr],
                  q, cb * 128 + n * 16 + ln15);
        }
  }
#undef COMPUTE
#undef STAGE_B

  // final cross-lane merge over ln15 group + classification
  #pragma unroll
  for (int m = 0; m < 2; ++m)
    #pragma unroll
    for (int rr = 0; rr < 4; ++rr) {
      float m1 = M1[m][rr], m2 = M2[m][rr], m3 = M3[m][rr];
      int i1 = I1[m][rr], i2 = I2[m][rr];
      #pragma unroll
      for (int sh = 1; sh <= 8; sh <<= 1) {
        float o1 = __shfl_xor(m1, sh); int oi1 = __shfl_xor(i1, sh);
        float o2 = __shfl_xor(m2, sh); int oi2 = __shfl_xor(i2, sh);
        float o3 = __shfl_xor(m3, sh);
        rec_ins(m1, m2, m3, i1, i2, o1, oi1);
        rec_ins(m1, m2, m3, i1, i2, o2, oi2);
        m3 = fminf(m3, o3);
      }
      if (ln15 == 0) {
        int row = rowOff + rowA0 + wave * 32 + m * 16 + ln4 * 4 + rr;
        labels[row] = i1;
        atomicAdd(&cnt[i1], 1);
        if (m2 <= m1 + SMARGIN) {
          if (m3 <= m1 + SMARGIN) {
            int s = atomicAdd(nscan, 1); scans[s] = row;
          } else {
            int p = atomicAdd(npairs, 1); pairs[p] = make_int4(row, i1, i2, 0);
          }
        }
      }
    }
}

// ---------------- exact rescore: 2-candidate rows ----------------
__global__ __launch_bounds__(256) void k_pairs(
    const float* __restrict__ E, const float* __restrict__ C,
    const float* __restrict__ x2, const float* __restrict__ c2,
    const int4* __restrict__ pairs, const int* __restrict__ npairs,
    int* __restrict__ labels, int* __restrict__ cnt) {
  int n = *npairs;
  int stride = gridDim.x * 256;
  for (int i = blockIdx.x * 256 + threadIdx.x; i < n; i += stride) {
    int4 p = pairs[i];
    float d1 = dist_exact(E, C, x2, c2, p.x, p.y);
    float d2 = dist_exact(E, C, x2, c2, p.x, p.z);
    int nw = (d2 < d1 || (d2 == d1 && p.z < p.y)) ? p.z : p.y;
    if (nw != p.y) {
      labels[p.x] = nw;
      atomicSub(&cnt[p.y], 1);
      atomicAdd(&cnt[nw], 1);
    }
  }
}

// ---------------- exact rescore: full-scan rows ----------------
__global__ __launch_bounds__(256) void k_scan(
    const float* __restrict__ E, const float* __restrict__ C,
    const float* __restrict__ x2, const float* __restrict__ c2,
    const int* __restrict__ scans, const int* __restrict__ nscan,
    int* __restrict__ labels, int* __restrict__ cnt) {
  __shared__ float sd[256];
  __shared__ int sj[256];
  int ns = *nscan;
  for (int s = blockIdx.x; s < ns; s += gridDim.x) {
    int row = scans[s];
    float bd = 3.4e38f; int bj = 0x7fffffff;
    for (int jj = 0; jj < 8; ++jj) {
      int j = jj * 256 + threadIdx.x;
      float d = dist_exact(E, C, x2, c2, row, j);
      if (d < bd || (d == bd && j < bj)) { bd = d; bj = j; }
    }
    sd[threadIdx.x] = bd; sj[threadIdx.x] = bj;
    __syncthreads();
    for (int st = 128; st > 0; st >>= 1) {
      if (threadIdx.x < st) {
        float od = sd[threadIdx.x + st]; int oj = sj[threadIdx.x + st];
        if (od < sd[threadIdx.x] || (od == sd[threadIdx.x] && oj < sj[threadIdx.x])) {
          sd[threadIdx.x] = od; sj[threadIdx.x] = oj;
        }
      }
      __syncthreads();
    }
    if (threadIdx.x == 0) {
      int nw = sj[0];
      int old = labels[row];
      if (nw != old) {
        labels[row] = nw;
        atomicSub(&cnt[old], 1);
        atomicAdd(&cnt[nw], 1);
      }
    }
    __syncthreads();
  }
}

// ---------------- exclusive scan over 2048 counts (Blelloch) ------------
__global__ __launch_bounds__(1024) void k_prefix(const int* __restrict__ cnt,
                                                 int* __restrict__ offs,
                                                 int* __restrict__ cursors) {
  __shared__ int s[KC];
  int t = threadIdx.x;
  s[t] = cnt[t]; s[t + 1024] = cnt[t + 1024];
  int offset = 1;
  for (int d = KC >> 1; d > 0; d >>= 1) {
    __syncthreads();
    if (t < d) {
      int ai = offset * (2 * t + 1) - 1;
      int bi = offset * (2 * t + 2) - 1;
      s[bi] += s[ai];
    }
    offset <<= 1;
  }
  __syncthreads();
  if (t == 0) s[KC - 1] = 0;
  for (int d = 1; d < KC; d <<= 1) {
    offset >>= 1;
    __syncthreads();
    if (t < d) {
      int ai = offset * (2 * t + 1) - 1;
      int bi = offset * (2 * t + 2) - 1;
      int tmp = s[ai]; s[ai] = s[bi]; s[bi] += tmp;
    }
  }
  __syncthreads();
  offs[t] = s[t];               cursors[t] = s[t];
  offs[t + 1024] = s[t + 1024]; cursors[t + 1024] = s[t + 1024];
  if (t == 0) offs[KC] = NS;
}

// ---------------- scatter rows into label-sorted order (+label array) ----
__global__ void k_scatter(const int* __restrict__ labels, int* __restrict__ cursors,
                          int* __restrict__ sorted, int* __restrict__ slab,
                          float* __restrict__ out_labels) {
  int i = blockIdx.x * 256 + threadIdx.x;
  if (i < NS) {
    int lab = labels[i];
    out_labels[i] = (float)lab;
    int pos = atomicAdd(&cursors[lab], 1);
    sorted[pos] = i;
    slab[pos] = lab;
  }
}

// ---------------- balanced segmented accumulate over sorted rows --------
__global__ __launch_bounds__(256) void k_accum3(
    const float* __restrict__ E, const float* __restrict__ C,
    const int* __restrict__ sorted, const int* __restrict__ slab,
    float* __restrict__ seg, double* __restrict__ loss) {
  const int d = threadIdx.x;
  const int beg = blockIdx.x * ACHUNK;
  const int end = beg + ACHUNK;
  int cur = slab[beg];
  float sum = 0.0f;
  double lp = 0.0;
  for (int i = beg; i < end; ++i) {
    int lab = slab[i];
    if (lab != cur) {
      unsafeAtomicAdd(&seg[(size_t)cur * DD + d], sum);
      sum = 0.0f; cur = lab;
    }
    float x = E[(size_t)sorted[i] * DD + d];
    sum += x;
    float c = C[(size_t)lab * DD + d];
    float df = x - c;
    lp += (double)df * (double)df;
  }
  unsafeAtomicAdd(&seg[(size_t)cur * DD + d], sum);
  #pragma unroll
  for (int o = 32; o >= 1; o >>= 1) lp += __shfl_down(lp, o);
  __shared__ double wsum[4];
  int lane = d & 63, wv = d >> 6;
  if (lane == 0) wsum[wv] = lp;
  __syncthreads();
  if (d == 0) unsafeAtomicAdd(loss, wsum[0] + wsum[1] + wsum[2] + wsum[3]);
}

// ---------------- finalize centers, counts, loss ----------------
__global__ void k_final2(const float* __restrict__ C, const int* __restrict__ counts0,
                         const int* __restrict__ offs, float* __restrict__ out_centers,
                         float* __restrict__ out_counts, float* __restrict__ out_loss,
                         const double* __restrict__ loss) {
  int i = blockIdx.x * 256 + threadIdx.x;
  if (i < KC * DD) {
    int k = i >> 8;
    float c0 = (float)counts0[k];
    float nc = c0 + (float)(offs[k + 1] - offs[k]);
    out_centers[i] = (c0 * C[i] + out_centers[i]) / nc;
  }
  if (i < KC) out_counts[i] = (float)counts0[i] + (float)(offs[i + 1] - offs[i]);
  if (i == 0) out_loss[0] = (float)(loss[0] / (double)NS);
}

extern "C" void kernel_launch(void* const* d_in, const int* in_sizes, int n_in,
                              void* d_out, int out_size, void* d_ws, size_t ws_size,
                              hipStream_t stream) {
  const float* E = (const float*)d_in[0];
  const float* C = (const float*)d_in[1];
  const int* counts0 = (const int*)d_in[2];

  float* out = (float*)d_out;
  float* out_labels  = out;                     // [NS]
  float* out_loss    = out + NS;                // [1]
  float* out_centers = out + NS + 1;            // [KC*DD] (doubles as seg acc)
  float* out_counts  = out + NS + 1 + KC * DD;  // [KC]

  char* ws = (char*)d_ws;
  size_t o = 0;
  auto alloc = [&](size_t bytes) -> void* {
    void* p = ws + o;
    o += (bytes + 255) & ~(size_t)255;
    return p;
  };
  // zero-region: loss(8) @0, npairs @16, nscan @20, cnt[KC] @256
  char* zr = (char*)alloc(256 + 4 * KC);
  double* loss_acc = (double*)zr;
  int* npairs = (int*)(zr + 16);
  int* nscan  = (int*)(zr + 20);
  int* cnt    = (int*)(zr + 256);
  int*   labels  = (int*)alloc(4 * (size_t)NS);
  float* x2      = (float*)alloc(4 * (size_t)NS);
  float* c2      = (float*)alloc(4 * KC);
  int*   offs    = (int*)alloc(4 * (KC + 1));
  int*   cursors = (int*)alloc(4 * KC);
  int*   sorted  = (int*)alloc(4 * (size_t)NS);
  int*   slab    = (int*)alloc(4 * (size_t)NS);
  unsigned short* CX = (unsigned short*)alloc(2 * (size_t)KC * 256);
  int4*  pairs   = (int4*)alloc(16 * (size_t)NS);
  int*   scans   = (int*)alloc(4 * (size_t)NS);

  // EX chunk (rows of 256 fp16 = 512 B): full NS if it fits, else halve
  size_t avail = (ws_size > o) ? (ws_size - o) : 0;
  int CH = NS;
  while (CH > 2048 && (size_t)CH * 512 > avail) CH >>= 1;
  unsigned short* EX = (unsigned short*)alloc((size_t)CH * 512);
  int NCH = NS / CH;

  hipMemsetAsync(zr, 0, 256 + 4 * KC, stream);
  hipMemsetAsync(out_centers, 0, sizeof(float) * KC * DD, stream);

  hipLaunchKernelGGL(k_prep, dim3(KC / 32), dim3(256), 0, stream, C, c2, CX);

  for (int ch = 0; ch < NCH; ++ch) {
    hipLaunchKernelGGL(k_prep, dim3(CH / 32), dim3(256), 0, stream,
                       E + (size_t)ch * CH * DD, x2 + (size_t)ch * CH, EX);
    hipLaunchKernelGGL(k_screenF, dim3(CH / 128), dim3(256), 0, stream,
                       EX, CX, c2, labels, pairs, scans, npairs, nscan, cnt,
                       ch * CH);
  }

  hipLaunchKernelGGL(k_pairs, dim3(64), dim3(256), 0, stream,
                     E, C, x2, c2, pairs, npairs, labels, cnt);
  hipLaunchKernelGGL(k_scan, dim3(128), dim3(256), 0, stream,
                     E, C, x2, c2, scans, nscan, labels, cnt);
  hipLaunchKernelGGL(k_prefix, dim3(1), dim3(1024), 0, stream, cnt, offs, cursors);
  hipLaunchKernelGGL(k_scatter, dim3(NS / 256), dim3(256), 0, stream,
                     labels, cursors, sorted, slab, out_labels);
  hipLaunchKernelGGL(k_accum3, dim3(NS / ACHUNK), dim3(256), 0, stream,
                     E, C, sorted, slab, out_centers, loss_acc);
  hipLaunchKernelGGL(k_final2, dim3((KC * DD + 255) / 256), dim3(256), 0, stream,
                     C, counts0, offs, out_centers, out_counts, out_loss, loss_acc);
}

// Round 18
// 678.870 us; speedup vs baseline: 1.3295x; 1.3295x over previous
//
#include <hip/hip_runtime.h>

typedef _Float16 f16x8 __attribute__((ext_vector_type(8)));
typedef float f32x4 __attribute__((ext_vector_type(4)));

#define NS 131072
#define KC 2048
#define DD 256
#define SMARGIN 0.12f
#define ACHUNK 128

struct Rec16 { float m1, m2, m3; unsigned ii; };  // ii = i1 | (i2<<16)

// ---------------- helpers ----------------
__device__ __forceinline__ unsigned umin_(unsigned a, unsigned b) { return a < b ? a : b; }
__device__ __forceinline__ unsigned umax_(unsigned a, unsigned b) { return a > b ? a : b; }

__device__ __forceinline__ void async16(void* lds, const void* g) {
  __builtin_amdgcn_global_load_lds(
      (const __attribute__((address_space(1))) unsigned*)g,
      (__attribute__((address_space(3))) unsigned*)lds, 16, 0, 0);
}

__device__ __forceinline__ void rec_ins(float& m1, float& m2, float& m3,
                                        int& i1, int& i2, float q, int i) {
  if (q < m1 || (q == m1 && i < i1)) {
    m3 = m2; m2 = m1; i2 = i1; m1 = q; i1 = i;
  } else if (q < m2 || (q == m2 && i < i2)) {
    m3 = m2; m2 = q; i2 = i;
  } else if (q < m3) {
    m3 = q;
  }
}

// exact fp32 distance: bit-identical to the verified round-2/3 chain
__device__ __forceinline__ float dist_exact(const float* __restrict__ E,
                                            const float* __restrict__ C,
                                            const float* __restrict__ x2,
                                            const float* __restrict__ c2,
                                            int row, int j) {
  const float* e = E + (size_t)row * DD;
  const float* c = C + (size_t)j * DD;
  float acc = 0.0f;
  #pragma unroll 8
  for (int k = 0; k < DD; ++k) acc = fmaf(e[k], c[k], acc);
  return __fadd_rn(__fsub_rn(x2[row], __fmul_rn(2.0f, acc)), c2[j]);
}

// ---------------- fused prep: coalesced load + fp16 + numpy-exact norm --
// (validated in rounds 14/16)
__global__ __launch_bounds__(256) void k_prep(const float* __restrict__ A,
                                              float* __restrict__ out,
                                              unsigned short* __restrict__ AX) {
  __shared__ float sf[32][260];  // padded: conflict-free chain reads
  const int tid = threadIdx.x;
  const size_t base = (size_t)blockIdx.x * 32 * 256;
  const float4* ga = (const float4*)(A + base);
  ushort4* gx = (ushort4*)(AX + base);
  #pragma unroll
  for (int i = 0; i < 8; ++i) {
    int idx = tid + i * 256;
    float4 v = ga[idx];
    int row = idx >> 6, c4 = idx & 63;
    *(float4*)&sf[row][c4 * 4] = v;
    union { _Float16 h; unsigned short u; } c0, c1, c2, c3;
    c0.h = (_Float16)v.x; c1.h = (_Float16)v.y;
    c2.h = (_Float16)v.z; c3.h = (_Float16)v.w;
    gx[idx] = make_ushort4(c0.u, c1.u, c2.u, c3.u);
  }
  __syncthreads();
  const int r = tid >> 3, l = tid & 7;
  float halfs[2];
  #pragma unroll
  for (int h = 0; h < 2; ++h) {
    float x = sf[r][h * 128 + l];
    float racc = __fmul_rn(x, x);
    #pragma unroll
    for (int i = 8; i < 128; i += 8) {
      float y = sf[r][h * 128 + i + l];
      racc = __fadd_rn(racc, __fmul_rn(y, y));
    }
    float t = __fadd_rn(racc, __shfl_xor(racc, 1));
    t = __fadd_rn(t, __shfl_xor(t, 2));
    t = __fadd_rn(t, __shfl_xor(t, 4));
    halfs[h] = t;
  }
  if (l == 0) out[blockIdx.x * 32 + r] = __fadd_rn(halfs[0], halfs[1]);
}

// ---------------- MFMA screening GEMM + per-row approx top-3 ------------
// Pure fp16-hi screen, K=256, 128x128 tile, BK=64, 4 waves (2x2).
// Counted-vmcnt 2-buffer pipeline (round-13 verbatim, proven @338us).
__global__ __launch_bounds__(256, 2) void k_screen16(
    const unsigned short* __restrict__ EX, const unsigned short* __restrict__ CX,
    const float* __restrict__ c2, Rec16* __restrict__ recs, int rowOff) {
  __shared__ char smem[65536];  // 2 bufs x (A 16K | B 16K)

  const int nwg = gridDim.x;
  const int b = blockIdx.x;
  const int swzb = (b & 7) * (nwg >> 3) + (b >> 3);   // bijective: nwg % 8 == 0
  const int colblk = swzb & 15, rowblk = swzb >> 4;

  const int tid = threadIdx.x;
  const int wave = tid >> 6, lane = tid & 63;
  const int ln15 = lane & 15, ln4 = lane >> 4;
  const int wr = wave >> 1, wc = wave & 1;
  const int rowA0 = rowblk * 128;
  const int colB0 = colblk * 128;
  const int rsw = ((lane & 7) ^ (lane >> 3)) << 3;  // src pre-swizzle (elems)

  const unsigned short* pA[4];
  const unsigned short* pB[4];
  {
    size_t ra = (size_t)(rowA0 + wave * 32 + (lane >> 3)) * 256 + rsw;
    size_t rb = (size_t)(colB0 + wave * 32 + (lane >> 3)) * 256 + rsw;
    #pragma unroll
    for (int t = 0; t < 4; ++t) {
      pA[t] = EX + ra + t * 2048;
      pB[t] = CX + rb + t * 2048;
    }
  }
  char* ldsA = smem + wave * 4096;
  char* ldsB = smem + 16384 + wave * 4096;
  const char* aaddr[2][4];
  const char* baddr[2][4];
  #pragma unroll
  for (int ks = 0; ks < 2; ++ks) {
    int sz = ((ks * 4 + ln4) ^ (ln15 & 7)) << 4;
    #pragma unroll
    for (int m = 0; m < 4; ++m)
      aaddr[ks][m] = smem + (wr * 64 + m * 16 + ln15) * 128 + sz;
    #pragma unroll
    for (int n = 0; n < 4; ++n)
      baddr[ks][n] = smem + 16384 + (wc * 64 + n * 16 + ln15) * 128 + sz;
  }

  f32x4 acc[4][4];
  #pragma unroll
  for (int m = 0; m < 4; ++m)
    #pragma unroll
    for (int n = 0; n < 4; ++n) acc[m][n] = (f32x4){0.f, 0.f, 0.f, 0.f};

#define VMW8() do { asm volatile("s_waitcnt vmcnt(8)" ::: "memory"); \
                    __builtin_amdgcn_sched_barrier(0); } while (0)
#define VMW0() do { asm volatile("s_waitcnt vmcnt(0)" ::: "memory"); \
                    __builtin_amdgcn_sched_barrier(0); } while (0)
#define BAR() __builtin_amdgcn_s_barrier();

#define STAGE(s) {                                                        \
    const int _buf = (s) & 1;                                             \
    const int _k = (s) * 64;                                              \
    _Pragma("unroll")                                                     \
    for (int t = 0; t < 4; ++t) {                                         \
      async16(ldsA + _buf * 32768 + t * 1024, pA[t] + _k);                \
      async16(ldsB + _buf * 32768 + t * 1024, pB[t] + _k);                \
    } }

#define COMPUTE(s) {                                                      \
    const int _bo = ((s) & 1) * 32768;                                    \
    _Pragma("unroll")                                                     \
    for (int ks = 0; ks < 2; ++ks) {                                      \
      f16x8 a[4], bb[4];                                                  \
      _Pragma("unroll")                                                   \
      for (int m = 0; m < 4; ++m)                                         \
        a[m] = *(const f16x8*)(aaddr[ks][m] + _bo);                       \
      _Pragma("unroll")                                                   \
      for (int n = 0; n < 4; ++n)                                         \
        bb[n] = *(const f16x8*)(baddr[ks][n] + _bo);                      \
      _Pragma("unroll")                                                   \
      for (int m = 0; m < 4; ++m)                                         \
        _Pragma("unroll")                                                 \
        for (int n = 0; n < 4; ++n)                                       \
          acc[m][n] = __builtin_amdgcn_mfma_f32_16x16x32_f16(             \
              a[m], bb[n], acc[m][n], 0, 0, 0);                           \
    } }

  // pipeline: 2 slabs in flight; wait only for the slab we consume
  STAGE(0); STAGE(1);
  VMW8(); BAR(); COMPUTE(0); BAR(); STAGE(2);
  VMW8(); BAR(); COMPUTE(1); BAR(); STAGE(3);
  VMW8(); BAR(); COMPUTE(2); BAR();
  VMW0(); BAR(); COMPUTE(3);
#undef STAGE
#undef COMPUTE

  __syncthreads();

  // ---- branchless epilogue: sortable-u32 keys, col packed in low 6 bits
  float c2v[4];
  #pragma unroll
  for (int n = 0; n < 4; ++n) c2v[n] = c2[colB0 + wc * 64 + n * 16 + ln15];

  unsigned* mb = (unsigned*)smem;  // [128 rows][2 wc][4 words]
  #pragma unroll
  for (int m = 0; m < 4; ++m) {
    #pragma unroll
    for (int rr = 0; rr < 4; ++rr) {
      unsigned k1 = 0xFFFFFFFFu, k2 = 0xFFFFFFFFu, k3 = 0xFFFFFFFFu;
      #pragma unroll
      for (int n = 0; n < 4; ++n) {
        float q = fmaf(-2.0f, acc[m][n][rr], c2v[n]);
        unsigned u = __float_as_uint(q);
        unsigned msk = 0x80000000u | (unsigned)((int)u >> 31);
        unsigned key = ((u ^ msk) & 0xFFFFFFC0u) | (unsigned)(n * 16 + ln15);
        unsigned t1 = umax_(k1, key);
        k1 = umin_(k1, key);
        unsigned t2 = umax_(k2, t1);
        k2 = umin_(k2, t1);
        k3 = umin_(k3, t2);
      }
      #pragma unroll
      for (int sh = 1; sh <= 8; sh <<= 1) {
        unsigned o1 = (unsigned)__shfl_xor((int)k1, sh);
        unsigned o2 = (unsigned)__shfl_xor((int)k2, sh);
        unsigned o3 = (unsigned)__shfl_xor((int)k3, sh);
        unsigned mm = umax_(k1, o1);
        k1 = umin_(k1, o1);
        unsigned tt = umin_(k2, o2);
        k2 = umin_(mm, tt);
        k3 = umin_(umin_(k3, o3), umax_(mm, tt));
      }
      if (ln15 == 0) {
        int row = wr * 64 + m * 16 + ln4 * 4 + rr;
        unsigned* p = mb + (row * 2 + wc) * 4;
        p[0] = k1; p[1] = k2; p[2] = k3;
      }
    }
  }
  __syncthreads();
  if (tid < 128) {
    const unsigned* p0 = mb + (tid * 2) * 4;
    const unsigned* p1 = mb + (tid * 2 + 1) * 4;
    auto dec = [](unsigned k) -> float {
      unsigned u = k & 0xFFFFFFC0u;
      u = (u & 0x80000000u) ? (u ^ 0x80000000u) : ~u;
      return __uint_as_float(u);
    };
    float m1 = dec(p0[0]); int i1 = colB0 + (int)(p0[0] & 63u);
    float m2 = dec(p0[1]); int i2 = colB0 + (int)(p0[1] & 63u);
    float m3 = dec(p0[2]);
    rec_ins(m1, m2, m3, i1, i2, dec(p1[0]), colB0 + 64 + (int)(p1[0] & 63u));
    rec_ins(m1, m2, m3, i1, i2, dec(p1[1]), colB0 + 64 + (int)(p1[1] & 63u));
    m3 = fminf(m3, dec(p1[2]));
    Rec16 outr;
    outr.m1 = m1; outr.m2 = m2; outr.m3 = m3;
    outr.ii = (unsigned)i1 | ((unsigned)i2 << 16);
    recs[((size_t)(rowOff + rowA0 + tid) << 4) + colblk] = outr;
  }
}

// ---------------- merge 16 col-block records; classify; hist ------------
__global__ __launch_bounds__(256) void k_merge(
    const Rec16* __restrict__ recs, int* __restrict__ labels,
    int4* __restrict__ pairs, int* __restrict__ scans,
    int* __restrict__ npairs, int* __restrict__ nscan, int* __restrict__ cnt) {
  int row = blockIdx.x * 256 + threadIdx.x;
  const Rec16* r = recs + ((size_t)row << 4);
  Rec16 a = r[0];
  float m1 = a.m1, m2 = a.m2, m3 = a.m3;
  int i1 = (int)(a.ii & 0xffffu), i2 = (int)(a.ii >> 16);
  #pragma unroll
  for (int cb = 1; cb < 16; ++cb) {
    Rec16 bb = r[cb];
    rec_ins(m1, m2, m3, i1, i2, bb.m1, (int)(bb.ii & 0xffffu));
    rec_ins(m1, m2, m3, i1, i2, bb.m2, (int)(bb.ii >> 16));
    m3 = fminf(m3, bb.m3);
  }
  labels[row] = i1;
  atomicAdd(&cnt[i1], 1);  // provisional; corrected by pairs/scan on change
  if (m2 <= m1 + SMARGIN) {
    if (m3 <= m1 + SMARGIN) {
      int s = atomicAdd(nscan, 1); scans[s] = row;
    } else {
      int p = atomicAdd(npairs, 1); pairs[p] = make_int4(row, i1, i2, 0);
    }
  }
}

// ---------------- exact rescore: 2-candidate rows ----------------
__global__ __launch_bounds__(256) void k_pairs(
    const float* __restrict__ E, const float* __restrict__ C,
    const float* __restrict__ x2, const float* __restrict__ c2,
    const int4* __restrict__ pairs, const int* __restrict__ npairs,
    int* __restrict__ labels, int* __restrict__ cnt) {
  int n = *npairs;
  int stride = gridDim.x * 256;
  for (int i = blockIdx.x * 256 + threadIdx.x; i < n; i += stride) {
    int4 p = pairs[i];
    float d1 = dist_exact(E, C, x2, c2, p.x, p.y);
    float d2 = dist_exact(E, C, x2, c2, p.x, p.z);
    int nw = (d2 < d1 || (d2 == d1 && p.z < p.y)) ? p.z : p.y;
    if (nw != p.y) {
      labels[p.x] = nw;
      atomicSub(&cnt[p.y], 1);
      atomicAdd(&cnt[nw], 1);
    }
  }
}

// ---------------- exact rescore: full-scan rows ----------------
__global__ __launch_bounds__(256) void k_scan(
    const float* __restrict__ E, const float* __restrict__ C,
    const float* __restrict__ x2, const float* __restrict__ c2,
    const int* __restrict__ scans, const int* __restrict__ nscan,
    int* __restrict__ labels, int* __restrict__ cnt) {
  __shared__ float sd[256];
  __shared__ int sj[256];
  int ns = *nscan;
  for (int s = blockIdx.x; s < ns; s += gridDim.x) {
    int row = scans[s];
    float bd = 3.4e38f; int bj = 0x7fffffff;
    for (int jj = 0; jj < 8; ++jj) {
      int j = jj * 256 + threadIdx.x;
      float d = dist_exact(E, C, x2, c2, row, j);
      if (d < bd || (d == bd && j < bj)) { bd = d; bj = j; }
    }
    sd[threadIdx.x] = bd; sj[threadIdx.x] = bj;
    __syncthreads();
    for (int st = 128; st > 0; st >>= 1) {
      if (threadIdx.x < st) {
        float od = sd[threadIdx.x + st]; int oj = sj[threadIdx.x + st];
        if (od < sd[threadIdx.x] || (od == sd[threadIdx.x] && oj < sj[threadIdx.x])) {
          sd[threadIdx.x] = od; sj[threadIdx.x] = oj;
        }
      }
      __syncthreads();
    }
    if (threadIdx.x == 0) {
      int nw = sj[0];
      int old = labels[row];
      if (nw != old) {
        labels[row] = nw;
        atomicSub(&cnt[old], 1);
        atomicAdd(&cnt[nw], 1);
      }
    }
    __syncthreads();
  }
}

// ---------------- exclusive scan over 2048 counts (Blelloch) ------------
__global__ __launch_bounds__(1024) void k_prefix(const int* __restrict__ cnt,
                                                 int* __restrict__ offs,
                                                 int* __restrict__ cursors) {
  __shared__ int s[KC];
  int t = threadIdx.x;
  s[t] = cnt[t]; s[t + 1024] = cnt[t + 1024];
  int offset = 1;
  for (int d = KC >> 1; d > 0; d >>= 1) {
    __syncthreads();
    if (t < d) {
      int ai = offset * (2 * t + 1) - 1;
      int bi = offset * (2 * t + 2) - 1;
      s[bi] += s[ai];
    }
    offset <<= 1;
  }
  __syncthreads();
  if (t == 0) s[KC - 1] = 0;
  for (int d = 1; d < KC; d <<= 1) {
    offset >>= 1;
    __syncthreads();
    if (t < d) {
      int ai = offset * (2 * t + 1) - 1;
      int bi = offset * (2 * t + 2) - 1;
      int tmp = s[ai]; s[ai] = s[bi]; s[bi] += tmp;
    }
  }
  __syncthreads();
  offs[t] = s[t];               cursors[t] = s[t];
  offs[t + 1024] = s[t + 1024]; cursors[t + 1024] = s[t + 1024];
  if (t == 0) offs[KC] = NS;
}

// ---------------- scatter rows into label-sorted order (+label array) ----
__global__ void k_scatter(const int* __restrict__ labels, int* __restrict__ cursors,
                          int* __restrict__ sorted, int* __restrict__ slab,
                          float* __restrict__ out_labels) {
  int i = blockIdx.x * 256 + threadIdx.x;
  if (i < NS) {
    int lab = labels[i];
    out_labels[i] = (float)lab;
    int pos = atomicAdd(&cursors[lab], 1);
    sorted[pos] = i;
    slab[pos] = lab;
  }
}

// ---------------- balanced segmented accumulate over sorted rows --------
__global__ __launch_bounds__(256) void k_accum3(
    const float* __restrict__ E, const float* __restrict__ C,
    const int* __restrict__ sorted, const int* __restrict__ slab,
    float* __restrict__ seg, double* __restrict__ loss) {
  const int d = threadIdx.x;
  const int beg = blockIdx.x * ACHUNK;
  const int end = beg + ACHUNK;
  int cur = slab[beg];
  float sum = 0.0f;
  double lp = 0.0;
  for (int i = beg; i < end; ++i) {
    int lab = slab[i];
    if (lab != cur) {
      unsafeAtomicAdd(&seg[(size_t)cur * DD + d], sum);
      sum = 0.0f; cur = lab;
    }
    float x = E[(size_t)sorted[i] * DD + d];
    sum += x;
    float c = C[(size_t)lab * DD + d];
    float df = x - c;
    lp += (double)df * (double)df;
  }
  unsafeAtomicAdd(&seg[(size_t)cur * DD + d], sum);
  #pragma unroll
  for (int o = 32; o >= 1; o >>= 1) lp += __shfl_down(lp, o);
  __shared__ double wsum[4];
  int lane = d & 63, wv = d >> 6;
  if (lane == 0) wsum[wv] = lp;
  __syncthreads();
  if (d == 0) unsafeAtomicAdd(loss, wsum[0] + wsum[1] + wsum[2] + wsum[3]);
}

// ---------------- finalize centers, counts, loss ----------------
__global__ void k_final2(const float* __restrict__ C, const int* __restrict__ counts0,
                         const int* __restrict__ offs, float* __restrict__ out_centers,
                         float* __restrict__ out_counts, float* __restrict__ out_loss,
                         const double* __restrict__ loss) {
  int i = blockIdx.x * 256 + threadIdx.x;
  if (i < KC * DD) {
    int k = i >> 8;
    float c0 = (float)counts0[k];
    float nc = c0 + (float)(offs[k + 1] - offs[k]);
    out_centers[i] = (c0 * C[i] + out_centers[i]) / nc;
  }
  if (i < KC) out_counts[i] = (float)counts0[i] + (float)(offs[i + 1] - offs[i]);
  if (i == 0) out_loss[0] = (float)(loss[0] / (double)NS);
}

extern "C" void kernel_launch(void* const* d_in, const int* in_sizes, int n_in,
                              void* d_out, int out_size, void* d_ws, size_t ws_size,
                              hipStream_t stream) {
  const float* E = (const float*)d_in[0];
  const float* C = (const float*)d_in[1];
  const int* counts0 = (const int*)d_in[2];

  float* out = (float*)d_out;
  float* out_labels  = out;                     // [NS]
  float* out_loss    = out + NS;                // [1]
  float* out_centers = out + NS + 1;            // [KC*DD] (doubles as seg acc)
  float* out_counts  = out + NS + 1 + KC * DD;  // [KC]

  char* ws = (char*)d_ws;
  size_t o = 0;
  auto alloc = [&](size_t bytes) -> void* {
    void* p = ws + o;
    o += (bytes + 255) & ~(size_t)255;
    return p;
  };
  // zero-region: loss(8) @0, npairs @16, nscan @20, cnt[KC] @256
  char* zr = (char*)alloc(256 + 4 * KC);
  double* loss_acc = (double*)zr;
  int* npairs = (int*)(zr + 16);
  int* nscan  = (int*)(zr + 20);
  int* cnt    = (int*)(zr + 256);
  int*   labels  = (int*)alloc(4 * (size_t)NS);
  float* x2      = (float*)alloc(4 * (size_t)NS);
  float* c2      = (float*)alloc(4 * KC);
  int*   offs    = (int*)alloc(4 * (KC + 1));
  int*   cursors = (int*)alloc(4 * KC);
  int*   sorted  = (int*)alloc(4 * (size_t)NS);
  int*   slab    = (int*)alloc(4 * (size_t)NS);
  unsigned short* CX = (unsigned short*)alloc(2 * (size_t)KC * 256);
  Rec16* recs    = (Rec16*)alloc(sizeof(Rec16) * (size_t)NS * 16);
  int4*  pairs   = (int4*)alloc(16 * (size_t)NS);
  int*   scans   = (int*)alloc(4 * (size_t)NS);

  // EX chunk (rows of 256 fp16 = 512 B): full NS if it fits, else halve
  size_t avail = (ws_size > o) ? (ws_size - o) : 0;
  int CH = NS;
  while (CH > 2048 && (size_t)CH * 512 > avail) CH >>= 1;
  unsigned short* EX = (unsigned short*)alloc((size_t)CH * 512);
  int NCH = NS / CH;

  hipMemsetAsync(zr, 0, 256 + 4 * KC, stream);
  hipMemsetAsync(out_centers, 0, sizeof(float) * KC * DD, stream);

  hipLaunchKernelGGL(k_prep, dim3(KC / 32), dim3(256), 0, stream, C, c2, CX);

  for (int ch = 0; ch < NCH; ++ch) {
    hipLaunchKernelGGL(k_prep, dim3(CH / 32), dim3(256), 0, stream,
                       E + (size_t)ch * CH * DD, x2 + (size_t)ch * CH, EX);
    hipLaunchKernelGGL(k_screen16, dim3((CH / 128) * 16), dim3(256), 0, stream,
                       EX, CX, c2, recs, ch * CH);
  }

  hipLaunchKernelGGL(k_merge, dim3(NS / 256), dim3(256), 0, stream,
                     recs, labels, pairs, scans, npairs, nscan, cnt);
  hipLaunchKernelGGL(k_pairs, dim3(64), dim3(256), 0, stream,
                     E, C, x2, c2, pairs, npairs, labels, cnt);
  hipLaunchKernelGGL(k_scan, dim3(128), dim3(256), 0, stream,
                     E, C, x2, c2, scans, nscan, labels, cnt);
  hipLaunchKernelGGL(k_prefix, dim3(1), dim3(1024), 0, stream, cnt, offs, cursors);
  hipLaunchKernelGGL(k_scatter, dim3(NS / 256), dim3(256), 0, stream,
                     labels, cursors, sorted, slab, out_labels);
  hipLaunchKernelGGL(k_accum3, dim3(NS / ACHUNK), dim3(256), 0, stream,
                     E, C, sorted, slab, out_centers, loss_acc);
  hipLaunchKernelGGL(k_final2, dim3((KC * DD + 255) / 256), dim3(256), 0, stream,
                     C, counts0, offs, out_centers, out_counts, out_loss, loss_acc);
}

// Round 19
// 632.109 us; speedup vs baseline: 1.4278x; 1.0740x over previous
//
#include <hip/hip_runtime.h>

typedef _Float16 f16x8 __attribute__((ext_vector_type(8)));
typedef float f32x4 __attribute__((ext_vector_type(4)));

#define NS 131072
#define KC 2048
#define DD 256
#define SMARGIN 0.12f
#define ACHUNK 64

struct Rec16 { float m1, m2, m3; unsigned ii; };  // ii = i1 | (i2<<16)

// ---------------- helpers ----------------
__device__ __forceinline__ unsigned umin_(unsigned a, unsigned b) { return a < b ? a : b; }
__device__ __forceinline__ unsigned umax_(unsigned a, unsigned b) { return a > b ? a : b; }

__device__ __forceinline__ void async16(void* lds, const void* g) {
  __builtin_amdgcn_global_load_lds(
      (const __attribute__((address_space(1))) unsigned*)g,
      (__attribute__((address_space(3))) unsigned*)lds, 16, 0, 0);
}

__device__ __forceinline__ void rec_ins(float& m1, float& m2, float& m3,
                                        int& i1, int& i2, float q, int i) {
  if (q < m1 || (q == m1 && i < i1)) {
    m3 = m2; m2 = m1; i2 = i1; m1 = q; i1 = i;
  } else if (q < m2 || (q == m2 && i < i2)) {
    m3 = m2; m2 = q; i2 = i;
  } else if (q < m3) {
    m3 = q;
  }
}

// exact fp32 distance: bit-identical to the verified round-2/3 chain
__device__ __forceinline__ float dist_exact(const float* __restrict__ E,
                                            const float* __restrict__ C,
                                            const float* __restrict__ x2,
                                            const float* __restrict__ c2,
                                            int row, int j) {
  const float* e = E + (size_t)row * DD;
  const float* c = C + (size_t)j * DD;
  float acc = 0.0f;
  #pragma unroll 8
  for (int k = 0; k < DD; ++k) acc = fmaf(e[k], c[k], acc);
  return __fadd_rn(__fsub_rn(x2[row], __fmul_rn(2.0f, acc)), c2[j]);
}

// ---------------- fused prep: coalesced load + fp16 + numpy-exact norm --
__global__ __launch_bounds__(256) void k_prep(const float* __restrict__ A,
                                              float* __restrict__ out,
                                              unsigned short* __restrict__ AX) {
  __shared__ float sf[32][260];  // padded: conflict-free chain reads
  const int tid = threadIdx.x;
  const size_t base = (size_t)blockIdx.x * 32 * 256;
  const float4* ga = (const float4*)(A + base);
  ushort4* gx = (ushort4*)(AX + base);
  #pragma unroll
  for (int i = 0; i < 8; ++i) {
    int idx = tid + i * 256;
    float4 v = ga[idx];
    int row = idx >> 6, c4 = idx & 63;
    *(float4*)&sf[row][c4 * 4] = v;
    union { _Float16 h; unsigned short u; } c0, c1, c2, c3;
    c0.h = (_Float16)v.x; c1.h = (_Float16)v.y;
    c2.h = (_Float16)v.z; c3.h = (_Float16)v.w;
    gx[idx] = make_ushort4(c0.u, c1.u, c2.u, c3.u);
  }
  __syncthreads();
  const int r = tid >> 3, l = tid & 7;
  float halfs[2];
  #pragma unroll
  for (int h = 0; h < 2; ++h) {
    float x = sf[r][h * 128 + l];
    float racc = __fmul_rn(x, x);
    #pragma unroll
    for (int i = 8; i < 128; i += 8) {
      float y = sf[r][h * 128 + i + l];
      racc = __fadd_rn(racc, __fmul_rn(y, y));
    }
    float t = __fadd_rn(racc, __shfl_xor(racc, 1));
    t = __fadd_rn(t, __shfl_xor(t, 2));
    t = __fadd_rn(t, __shfl_xor(t, 4));
    halfs[h] = t;
  }
  if (l == 0) out[blockIdx.x * 32 + r] = __fadd_rn(halfs[0], halfs[1]);
}

// ---------------- MFMA screening GEMM + per-row approx top-3 ------------
// Pure fp16-hi screen, K=256, 128x128 tile, BK=64, 4 waves (2x2).
// Counted-vmcnt 2-buffer pipeline (round-13 verbatim, proven @338us).
__global__ __launch_bounds__(256, 2) void k_screen16(
    const unsigned short* __restrict__ EX, const unsigned short* __restrict__ CX,
    const float* __restrict__ c2, Rec16* __restrict__ recs, int rowOff) {
  __shared__ char smem[65536];  // 2 bufs x (A 16K | B 16K)

  const int nwg = gridDim.x;
  const int b = blockIdx.x;
  const int swzb = (b & 7) * (nwg >> 3) + (b >> 3);   // bijective: nwg % 8 == 0
  const int colblk = swzb & 15, rowblk = swzb >> 4;

  const int tid = threadIdx.x;
  const int wave = tid >> 6, lane = tid & 63;
  const int ln15 = lane & 15, ln4 = lane >> 4;
  const int wr = wave >> 1, wc = wave & 1;
  const int rowA0 = rowblk * 128;
  const int colB0 = colblk * 128;
  const int rsw = ((lane & 7) ^ (lane >> 3)) << 3;  // src pre-swizzle (elems)

  const unsigned short* pA[4];
  const unsigned short* pB[4];
  {
    size_t ra = (size_t)(rowA0 + wave * 32 + (lane >> 3)) * 256 + rsw;
    size_t rb = (size_t)(colB0 + wave * 32 + (lane >> 3)) * 256 + rsw;
    #pragma unroll
    for (int t = 0; t < 4; ++t) {
      pA[t] = EX + ra + t * 2048;
      pB[t] = CX + rb + t * 2048;
    }
  }
  char* ldsA = smem + wave * 4096;
  char* ldsB = smem + 16384 + wave * 4096;
  const char* aaddr[2][4];
  const char* baddr[2][4];
  #pragma unroll
  for (int ks = 0; ks < 2; ++ks) {
    int sz = ((ks * 4 + ln4) ^ (ln15 & 7)) << 4;
    #pragma unroll
    for (int m = 0; m < 4; ++m)
      aaddr[ks][m] = smem + (wr * 64 + m * 16 + ln15) * 128 + sz;
    #pragma unroll
    for (int n = 0; n < 4; ++n)
      baddr[ks][n] = smem + 16384 + (wc * 64 + n * 16 + ln15) * 128 + sz;
  }

  f32x4 acc[4][4];
  #pragma unroll
  for (int m = 0; m < 4; ++m)
    #pragma unroll
    for (int n = 0; n < 4; ++n) acc[m][n] = (f32x4){0.f, 0.f, 0.f, 0.f};

#define VMW8() do { asm volatile("s_waitcnt vmcnt(8)" ::: "memory"); \
                    __builtin_amdgcn_sched_barrier(0); } while (0)
#define VMW0() do { asm volatile("s_waitcnt vmcnt(0)" ::: "memory"); \
                    __builtin_amdgcn_sched_barrier(0); } while (0)
#define BAR() __builtin_amdgcn_s_barrier();

#define STAGE(s) {                                                        \
    const int _buf = (s) & 1;                                             \
    const int _k = (s) * 64;                                              \
    _Pragma("unroll")                                                     \
    for (int t = 0; t < 4; ++t) {                                         \
      async16(ldsA + _buf * 32768 + t * 1024, pA[t] + _k);                \
      async16(ldsB + _buf * 32768 + t * 1024, pB[t] + _k);                \
    } }

#define COMPUTE(s) {                                                      \
    const int _bo = ((s) & 1) * 32768;                                    \
    _Pragma("unroll")                                                     \
    for (int ks = 0; ks < 2; ++ks) {                                      \
      f16x8 a[4], bb[4];                                                  \
      _Pragma("unroll")                                                   \
      for (int m = 0; m < 4; ++m)                                         \
        a[m] = *(const f16x8*)(aaddr[ks][m] + _bo);                       \
      _Pragma("unroll")                                                   \
      for (int n = 0; n < 4; ++n)                                         \
        bb[n] = *(const f16x8*)(baddr[ks][n] + _bo);                      \
      _Pragma("unroll")                                                   \
      for (int m = 0; m < 4; ++m)                                         \
        _Pragma("unroll")                                                 \
        for (int n = 0; n < 4; ++n)                                       \
          acc[m][n] = __builtin_amdgcn_mfma_f32_16x16x32_f16(             \
              a[m], bb[n], acc[m][n], 0, 0, 0);                           \
    } }

  STAGE(0); STAGE(1);
  VMW8(); BAR(); COMPUTE(0); BAR(); STAGE(2);
  VMW8(); BAR(); COMPUTE(1); BAR(); STAGE(3);
  VMW8(); BAR(); COMPUTE(2); BAR();
  VMW0(); BAR(); COMPUTE(3);
#undef STAGE
#undef COMPUTE

  __syncthreads();

  // ---- branchless epilogue: sortable-u32 keys, col packed in low 6 bits
  float c2v[4];
  #pragma unroll
  for (int n = 0; n < 4; ++n) c2v[n] = c2[colB0 + wc * 64 + n * 16 + ln15];

  unsigned* mb = (unsigned*)smem;  // [128 rows][2 wc][4 words]
  #pragma unroll
  for (int m = 0; m < 4; ++m) {
    #pragma unroll
    for (int rr = 0; rr < 4; ++rr) {
      unsigned k1 = 0xFFFFFFFFu, k2 = 0xFFFFFFFFu, k3 = 0xFFFFFFFFu;
      #pragma unroll
      for (int n = 0; n < 4; ++n) {
        float q = fmaf(-2.0f, acc[m][n][rr], c2v[n]);
        unsigned u = __float_as_uint(q);
        unsigned msk = 0x80000000u | (unsigned)((int)u >> 31);
        unsigned key = ((u ^ msk) & 0xFFFFFFC0u) | (unsigned)(n * 16 + ln15);
        unsigned t1 = umax_(k1, key);
        k1 = umin_(k1, key);
        unsigned t2 = umax_(k2, t1);
        k2 = umin_(k2, t1);
        k3 = umin_(k3, t2);
      }
      #pragma unroll
      for (int sh = 1; sh <= 8; sh <<= 1) {
        unsigned o1 = (unsigned)__shfl_xor((int)k1, sh);
        unsigned o2 = (unsigned)__shfl_xor((int)k2, sh);
        unsigned o3 = (unsigned)__shfl_xor((int)k3, sh);
        unsigned mm = umax_(k1, o1);
        k1 = umin_(k1, o1);
        unsigned tt = umin_(k2, o2);
        k2 = umin_(mm, tt);
        k3 = umin_(umin_(k3, o3), umax_(mm, tt));
      }
      if (ln15 == 0) {
        int row = wr * 64 + m * 16 + ln4 * 4 + rr;
        unsigned* p = mb + (row * 2 + wc) * 4;
        p[0] = k1; p[1] = k2; p[2] = k3;
      }
    }
  }
  __syncthreads();
  if (tid < 128) {
    const unsigned* p0 = mb + (tid * 2) * 4;
    const unsigned* p1 = mb + (tid * 2 + 1) * 4;
    auto dec = [](unsigned k) -> float {
      unsigned u = k & 0xFFFFFFC0u;
      u = (u & 0x80000000u) ? (u ^ 0x80000000u) : ~u;
      return __uint_as_float(u);
    };
    float m1 = dec(p0[0]); int i1 = colB0 + (int)(p0[0] & 63u);
    float m2 = dec(p0[1]); int i2 = colB0 + (int)(p0[1] & 63u);
    float m3 = dec(p0[2]);
    rec_ins(m1, m2, m3, i1, i2, dec(p1[0]), colB0 + 64 + (int)(p1[0] & 63u));
    rec_ins(m1, m2, m3, i1, i2, dec(p1[1]), colB0 + 64 + (int)(p1[1] & 63u));
    m3 = fminf(m3, dec(p1[2]));
    Rec16 outr;
    outr.m1 = m1; outr.m2 = m2; outr.m3 = m3;
    outr.ii = (unsigned)i1 | ((unsigned)i2 << 16);
    recs[((size_t)(rowOff + rowA0 + tid) << 4) + colblk] = outr;
  }
}

// ---------------- merge 16 col-block records; classify; hist ------------
__global__ __launch_bounds__(256) void k_merge(
    const Rec16* __restrict__ recs, int* __restrict__ labels,
    int4* __restrict__ pairs, int* __restrict__ scans,
    int* __restrict__ npairs, int* __restrict__ nscan, int* __restrict__ cnt) {
  int row = blockIdx.x * 256 + threadIdx.x;
  const Rec16* r = recs + ((size_t)row << 4);
  Rec16 a = r[0];
  float m1 = a.m1, m2 = a.m2, m3 = a.m3;
  int i1 = (int)(a.ii & 0xffffu), i2 = (int)(a.ii >> 16);
  #pragma unroll
  for (int cb = 1; cb < 16; ++cb) {
    Rec16 bb = r[cb];
    rec_ins(m1, m2, m3, i1, i2, bb.m1, (int)(bb.ii & 0xffffu));
    rec_ins(m1, m2, m3, i1, i2, bb.m2, (int)(bb.ii >> 16));
    m3 = fminf(m3, bb.m3);
  }
  labels[row] = i1;
  atomicAdd(&cnt[i1], 1);  // provisional; corrected by rescue on change
  if (m2 <= m1 + SMARGIN) {
    if (m3 <= m1 + SMARGIN) {
      int s = atomicAdd(nscan, 1); scans[s] = row;
    } else {
      int p = atomicAdd(npairs, 1); pairs[p] = make_int4(row, i1, i2, 0);
    }
  }
}

// ---------------- fused exact rescue: pairs (blocks<128) + scans --------
__global__ __launch_bounds__(256) void k_rescue(
    const float* __restrict__ E, const float* __restrict__ C,
    const float* __restrict__ x2, const float* __restrict__ c2,
    const int4* __restrict__ pairs, const int* __restrict__ npairs,
    const int* __restrict__ scans, const int* __restrict__ nscan,
    int* __restrict__ labels, int* __restrict__ cnt) {
  if (blockIdx.x < 128) {
    // 2-candidate rows, grid-stride over 128 blocks
    int n = *npairs;
    int stride = 128 * 256;
    for (int i = blockIdx.x * 256 + threadIdx.x; i < n; i += stride) {
      int4 p = pairs[i];
      float d1 = dist_exact(E, C, x2, c2, p.x, p.y);
      float d2 = dist_exact(E, C, x2, c2, p.x, p.z);
      int nw = (d2 < d1 || (d2 == d1 && p.z < p.y)) ? p.z : p.y;
      if (nw != p.y) {
        labels[p.x] = nw;
        atomicSub(&cnt[p.y], 1);
        atomicAdd(&cnt[nw], 1);
      }
    }
    return;
  }
  // full-scan rows, one row per block iteration over 256 blocks
  __shared__ float sd[256];
  __shared__ int sj[256];
  int ns = *nscan;
  for (int s = blockIdx.x - 128; s < ns; s += 256) {
    int row = scans[s];
    float bd = 3.4e38f; int bj = 0x7fffffff;
    for (int jj = 0; jj < 8; ++jj) {
      int j = jj * 256 + threadIdx.x;
      float d = dist_exact(E, C, x2, c2, row, j);
      if (d < bd || (d == bd && j < bj)) { bd = d; bj = j; }
    }
    sd[threadIdx.x] = bd; sj[threadIdx.x] = bj;
    __syncthreads();
    for (int st = 128; st > 0; st >>= 1) {
      if (threadIdx.x < st) {
        float od = sd[threadIdx.x + st]; int oj = sj[threadIdx.x + st];
        if (od < sd[threadIdx.x] || (od == sd[threadIdx.x] && oj < sj[threadIdx.x])) {
          sd[threadIdx.x] = od; sj[threadIdx.x] = oj;
        }
      }
      __syncthreads();
    }
    if (threadIdx.x == 0) {
      int nw = sj[0];
      int old = labels[row];
      if (nw != old) {
        labels[row] = nw;
        atomicSub(&cnt[old], 1);
        atomicAdd(&cnt[nw], 1);
      }
    }
    __syncthreads();
  }
}

// ---------------- exclusive scan over 2048 counts (Blelloch) ------------
__global__ __launch_bounds__(1024) void k_prefix(const int* __restrict__ cnt,
                                                 int* __restrict__ offs,
                                                 int* __restrict__ cursors) {
  __shared__ int s[KC];
  int t = threadIdx.x;
  s[t] = cnt[t]; s[t + 1024] = cnt[t + 1024];
  int offset = 1;
  for (int d = KC >> 1; d > 0; d >>= 1) {
    __syncthreads();
    if (t < d) {
      int ai = offset * (2 * t + 1) - 1;
      int bi = offset * (2 * t + 2) - 1;
      s[bi] += s[ai];
    }
    offset <<= 1;
  }
  __syncthreads();
  if (t == 0) s[KC - 1] = 0;
  for (int d = 1; d < KC; d <<= 1) {
    offset >>= 1;
    __syncthreads();
    if (t < d) {
      int ai = offset * (2 * t + 1) - 1;
      int bi = offset * (2 * t + 2) - 1;
      int tmp = s[ai]; s[ai] = s[bi]; s[bi] += tmp;
    }
  }
  __syncthreads();
  offs[t] = s[t];               cursors[t] = s[t];
  offs[t + 1024] = s[t + 1024]; cursors[t + 1024] = s[t + 1024];
  if (t == 0) offs[KC] = NS;
}

// ---------------- scatter rows into label-sorted order (+label array) ----
__global__ void k_scatter(const int* __restrict__ labels, int* __restrict__ cursors,
                          int* __restrict__ sorted, int* __restrict__ slab,
                          float* __restrict__ out_labels) {
  int i = blockIdx.x * 256 + threadIdx.x;
  if (i < NS) {
    int lab = labels[i];
    out_labels[i] = (float)lab;
    int pos = atomicAdd(&cursors[lab], 1);
    sorted[pos] = i;
    slab[pos] = lab;
  }
}

// ---------------- balanced segmented accumulate over sorted rows --------
__global__ __launch_bounds__(256) void k_accum3(
    const float* __restrict__ E, const float* __restrict__ C,
    const int* __restrict__ sorted, const int* __restrict__ slab,
    float* __restrict__ seg, double* __restrict__ loss) {
  const int d = threadIdx.x;
  const int beg = blockIdx.x * ACHUNK;
  const int end = beg + ACHUNK;
  int cur = slab[beg];
  float sum = 0.0f;
  double lp = 0.0;
  for (int i = beg; i < end; ++i) {
    int lab = slab[i];
    if (lab != cur) {
      unsafeAtomicAdd(&seg[(size_t)cur * DD + d], sum);
      sum = 0.0f; cur = lab;
    }
    float x = E[(size_t)sorted[i] * DD + d];
    sum += x;
    float c = C[(size_t)lab * DD + d];
    float df = x - c;
    lp += (double)df * (double)df;
  }
  unsafeAtomicAdd(&seg[(size_t)cur * DD + d], sum);
  #pragma unroll
  for (int o = 32; o >= 1; o >>= 1) lp += __shfl_down(lp, o);
  __shared__ double wsum[4];
  int lane = d & 63, wv = d >> 6;
  if (lane == 0) wsum[wv] = lp;
  __syncthreads();
  if (d == 0) unsafeAtomicAdd(loss, wsum[0] + wsum[1] + wsum[2] + wsum[3]);
}

// ---------------- finalize centers, counts, loss ----------------
__global__ void k_final2(const float* __restrict__ C, const int* __restrict__ counts0,
                         const int* __restrict__ offs, float* __restrict__ out_centers,
                         float* __restrict__ out_counts, float* __restrict__ out_loss,
                         const double* __restrict__ loss) {
  int i = blockIdx.x * 256 + threadIdx.x;
  if (i < KC * DD) {
    int k = i >> 8;
    float c0 = (float)counts0[k];
    float nc = c0 + (float)(offs[k + 1] - offs[k]);
    out_centers[i] = (c0 * C[i] + out_centers[i]) / nc;
  }
  if (i < KC) out_counts[i] = (float)counts0[i] + (float)(offs[i + 1] - offs[i]);
  if (i == 0) out_loss[0] = (float)(loss[0] / (double)NS);
}

extern "C" void kernel_launch(void* const* d_in, const int* in_sizes, int n_in,
                              void* d_out, int out_size, void* d_ws, size_t ws_size,
                              hipStream_t stream) {
  const float* E = (const float*)d_in[0];
  const float* C = (const float*)d_in[1];
  const int* counts0 = (const int*)d_in[2];

  float* out = (float*)d_out;
  float* out_labels  = out;                     // [NS]
  float* out_loss    = out + NS;                // [1]
  float* out_centers = out + NS + 1;            // [KC*DD] (doubles as seg acc)
  float* out_counts  = out + NS + 1 + KC * DD;  // [KC]

  char* ws = (char*)d_ws;
  size_t o = 0;
  auto alloc = [&](size_t bytes) -> void* {
    void* p = ws + o;
    o += (bytes + 255) & ~(size_t)255;
    return p;
  };
  // zero-region: loss(8) @0, npairs @16, nscan @20, cnt[KC] @256
  char* zr = (char*)alloc(256 + 4 * KC);
  double* loss_acc = (double*)zr;
  int* npairs = (int*)(zr + 16);
  int* nscan  = (int*)(zr + 20);
  int* cnt    = (int*)(zr + 256);
  int*   labels  = (int*)alloc(4 * (size_t)NS);
  float* x2      = (float*)alloc(4 * (size_t)NS);
  float* c2      = (float*)alloc(4 * KC);
  int*   offs    = (int*)alloc(4 * (KC + 1));
  int*   cursors = (int*)alloc(4 * KC);
  int*   sorted  = (int*)alloc(4 * (size_t)NS);
  int*   slab    = (int*)alloc(4 * (size_t)NS);
  unsigned short* CX = (unsigned short*)alloc(2 * (size_t)KC * 256);
  Rec16* recs    = (Rec16*)alloc(sizeof(Rec16) * (size_t)NS * 16);
  int4*  pairs   = (int4*)alloc(16 * (size_t)NS);
  int*   scans   = (int*)alloc(4 * (size_t)NS);

  // EX chunk (rows of 256 fp16 = 512 B): full NS if it fits, else halve
  size_t avail = (ws_size > o) ? (ws_size - o) : 0;
  int CH = NS;
  while (CH > 2048 && (size_t)CH * 512 > avail) CH >>= 1;
  unsigned short* EX = (unsigned short*)alloc((size_t)CH * 512);
  int NCH = NS / CH;

  hipMemsetAsync(zr, 0, 256 + 4 * KC, stream);
  hipMemsetAsync(out_centers, 0, sizeof(float) * KC * DD, stream);

  hipLaunchKernelGGL(k_prep, dim3(KC / 32), dim3(256), 0, stream, C, c2, CX);

  for (int ch = 0; ch < NCH; ++ch) {
    hipLaunchKernelGGL(k_prep, dim3(CH / 32), dim3(256), 0, stream,
                       E + (size_t)ch * CH * DD, x2 + (size_t)ch * CH, EX);
    hipLaunchKernelGGL(k_screen16, dim3((CH / 128) * 16), dim3(256), 0, stream,
                       EX, CX, c2, recs, ch * CH);
  }

  hipLaunchKernelGGL(k_merge, dim3(NS / 256), dim3(256), 0, stream,
                     recs, labels, pairs, scans, npairs, nscan, cnt);
  hipLaunchKernelGGL(k_rescue, dim3(384), dim3(256), 0, stream,
                     E, C, x2, c2, pairs, npairs, scans, nscan, labels, cnt);
  hipLaunchKernelGGL(k_prefix, dim3(1), dim3(1024), 0, stream, cnt, offs, cursors);
  hipLaunchKernelGGL(k_scatter, dim3(NS / 256), dim3(256), 0, stream,
                     labels, cursors, sorted, slab, out_labels);
  hipLaunchKernelGGL(k_accum3, dim3(NS / ACHUNK), dim3(256), 0, stream,
                     E, C, sorted, slab, out_centers, loss_acc);
  hipLaunchKernelGGL(k_final2, dim3((KC * DD + 255) / 256), dim3(256), 0, stream,
                     C, counts0, offs, out_centers, out_counts, out_loss, loss_acc);
}